// Round 1
// baseline (72.831 us; speedup 1.0000x reference)
//
#include <hip/hip_runtime.h>

// ARIMA_59373627900097 — forward loss on MI355X.
// Structure: sliding 32-window RevIN + diff + AR dot + denorm, squared-error
// reduction over ~1M positions. Memory-trivial (4 MB input); latency-bound.

#define PP   32      // AR window P
#define T0V  33      // t0 = max(P,Q)+1
#define BLK  256

__global__ __launch_bounds__(BLK) void arima_main(
    const float* __restrict__ y, const float* __restrict__ arw,
    const float* __restrict__ arb, const float* __restrict__ rvw,
    const float* __restrict__ rvb, float* __restrict__ partial,
    int S, int T)
{
    __shared__ float sh[BLK + PP];   // y[1+base .. 1+base+287]
    __shared__ float wsh[PP];
    __shared__ float red[BLK / 64];

    const int tid  = threadIdx.x;
    const int base = blockIdx.x * BLK;

    // Stage tile: sh[i] = y[1 + base + i]. Window win[t][j] = y[t+1+j] = sh[tid+j];
    // target y[t0+t] = y[t+33] = sh[tid+32]. One global read per element.
    int gi = 1 + base + tid;
    sh[tid] = (gi < S) ? y[gi] : 0.0f;
    if (tid < PP) {
        int gi2 = gi + BLK;
        sh[BLK + tid] = (gi2 < S) ? y[gi2] : 0.0f;
        wsh[tid] = arw[tid];
    }
    __syncthreads();

    const float rw   = rvw[0];
    const float rb   = rvb[0];
    const float bias = arb[0];

    const int t = base + tid;
    float val = 0.0f;
    if (t < T) {
        // two-pass mean/var, matches jnp.mean + jnp.var (ddof=0)
        float s = 0.0f;
        #pragma unroll
        for (int j = 0; j < PP; ++j) s += sh[tid + j];
        const float mean = s * (1.0f / PP);

        float v = 0.0f;
        #pragma unroll
        for (int j = 0; j < PP; ++j) { float d = sh[tid + j] - mean; v += d * d; }
        const float stdv  = sqrtf(v * (1.0f / PP) + 1e-5f);
        const float scale = rw / stdv;

        // norm[j] = (x-mean)/std*rw + rb; dser[0]=norm[0], dser[j]=norm[j]-norm[j-1]
        // ar = dser . w + bias; pred_d = dser[P-1] + ar
        float acc  = bias;
        float prev = 0.0f, prev2 = 0.0f;
        #pragma unroll
        for (int j = 0; j < PP; ++j) {
            float nj = (sh[tid + j] - mean) * scale + rb;
            float d  = (j == 0) ? nj : (nj - prev);
            acc += d * wsh[j];
            prev2 = prev;
            prev  = nj;
        }
        const float pred_d = (prev - prev2) + acc;
        const float pred   = (pred_d - rb) / (rw + 1e-10f) * stdv + mean;
        const float err    = sh[tid + PP] - pred;   // y[t0+t] - pred
        val = err * err;
    }

    // wave(64) shuffle reduce -> cross-wave LDS reduce -> one partial per block
    #pragma unroll
    for (int o = 32; o > 0; o >>= 1) val += __shfl_down(val, o, 64);
    if ((tid & 63) == 0) red[tid >> 6] = val;
    __syncthreads();
    if (tid == 0) partial[blockIdx.x] = red[0] + red[1] + red[2] + red[3];
}

__global__ __launch_bounds__(BLK) void arima_finish(
    const float* __restrict__ partial, int nblocks,
    const float* __restrict__ y, float* __restrict__ out, int S)
{
    __shared__ float red[BLK / 64];
    const int tid = threadIdx.x;

    float s = 0.0f;
    for (int i = tid; i < nblocks; i += BLK) s += partial[i];
    #pragma unroll
    for (int o = 32; o > 0; o >>= 1) s += __shfl_down(s, o, 64);
    if ((tid & 63) == 0) red[tid >> 6] = s;
    __syncthreads();

    if (tid == 0) {
        float tot = red[0] + red[1] + red[2] + red[3];
        float head = 0.0f;
        for (int i = 0; i < T0V; ++i) { float v = y[i]; head += v * v; }
        out[0] = (tot + head) / (float)S;
    }
}

extern "C" void kernel_launch(void* const* d_in, const int* in_sizes, int n_in,
                              void* d_out, int out_size, void* d_ws, size_t ws_size,
                              hipStream_t stream)
{
    const float* y   = (const float*)d_in[0];
    const float* arw = (const float*)d_in[1];
    const float* arb = (const float*)d_in[2];
    const float* rvw = (const float*)d_in[3];
    const float* rvb = (const float*)d_in[4];
    float* out       = (float*)d_out;
    float* partial   = (float*)d_ws;   // nblocks floats, well under ws_size

    const int S = in_sizes[0];
    const int T = S - T0V;
    const int nblocks = (T + BLK - 1) / BLK;

    arima_main<<<nblocks, BLK, 0, stream>>>(y, arw, arb, rvw, rvb, partial, S, T);
    arima_finish<<<1, BLK, 0, stream>>>(partial, nblocks, y, out, S);
}